// Round 1
// baseline (721.813 us; speedup 1.0000x reference)
//
#include <hip/hip_runtime.h>

typedef unsigned long long u64;

// ---------------- amax over |emb| ----------------
__global__ void amax_kernel(const float* __restrict__ emb, unsigned int* __restrict__ out) {
    const int n4 = (32000 * 256) / 4;
    float m = 0.0f;
    const float4* e4 = (const float4*)emb;
    for (int i = blockIdx.x * blockDim.x + threadIdx.x; i < n4; i += gridDim.x * blockDim.x) {
        float4 v = e4[i];
        m = fmaxf(m, fmaxf(fmaxf(fabsf(v.x), fabsf(v.y)), fmaxf(fabsf(v.z), fabsf(v.w))));
    }
#pragma unroll
    for (int off = 32; off > 0; off >>= 1) m = fmaxf(m, __shfl_down(m, off, 64));
    if ((threadIdx.x & 63) == 0) atomicMax(out, __float_as_uint(m));
}

// ---------------- bit packing ----------------
// word t covers 64 consecutive floats of its source matrix (rows are multiples of 64)
__global__ void pack_kernel(const float* __restrict__ emb, const float* __restrict__ Wih0,
                            const float* __restrict__ Whh0, const float* __restrict__ Wih1,
                            const float* __restrict__ Whh1, const float* __restrict__ Wfc,
                            const unsigned int* __restrict__ amax_bits,
                            u64* __restrict__ embb, u64* __restrict__ w0b, u64* __restrict__ u0b,
                            u64* __restrict__ w1b, u64* __restrict__ u1b, u64* __restrict__ wfcb) {
    int t = blockIdx.x * blockDim.x + threadIdx.x;
    const float* src;
    u64* dst;
    bool is_emb = false;
    if (t < 128000)      { src = emb + (long long)t * 64; dst = embb + t; is_emb = true; }
    else if (t < 130048) { int i = t - 128000; src = Wih0 + i * 64; dst = w0b + i; }
    else if (t < 134144) { int i = t - 130048; src = Whh0 + i * 64; dst = u0b + i; }
    else if (t < 138240) { int i = t - 134144; src = Wih1 + i * 64; dst = w1b + i; }
    else if (t < 142336) { int i = t - 138240; src = Whh1 + i * 64; dst = u1b + i; }
    else if (t < 142344) { int i = t - 142336; src = Wfc + i * 64; dst = wfcb + i; }
    else return;

    u64 bits = 0;
    if (is_emb) {
        float amax = __uint_as_float(*amax_bits) + 1e-12f;
        float s = exp2f(ceilf(log2f(amax / 127.0f)));
#pragma unroll
        for (int j = 0; j < 64; ++j) {
            float r = rintf(src[j] / s);           // round-half-even, matches jnp.round
            bits |= (u64)(r >= 0.0f) << j;         // -0.0 >= 0 is true, matches where(x>=0,..)
        }
    } else {
#pragma unroll
        for (int j = 0; j < 64; ++j) bits |= (u64)(src[j] >= 0.0f) << j;
    }
    *dst = bits;
}

// ---------------- the sequential scan: both layers pipelined ----------------
// grid = B(64) blocks, block = H(512) threads, thread = one h unit.
__global__ __launch_bounds__(512, 2) void scan_kernel(
    const int* __restrict__ text,
    const float* __restrict__ bih0, const float* __restrict__ bhh0,
    const float* __restrict__ bih1, const float* __restrict__ bhh1,
    const u64* __restrict__ embb, const u64* __restrict__ w0b, const u64* __restrict__ u0b,
    const u64* __restrict__ w1b, const u64* __restrict__ u1b,
    u64* __restrict__ hT0, u64* __restrict__ hT1) {
    __shared__ int txt[512];
    __shared__ u64 xb[4];     // binarized input embedding bits for current t
    __shared__ u64 h0s[8];    // layer-0 hidden state bits
    __shared__ u64 h1s[8];    // layer-1 hidden state bits

    const int tid = threadIdx.x;
    const int b = blockIdx.x;
    txt[tid & 511] = text[b * 512 + (tid & 511)];

    // per-thread weight rows, bit-packed, live in VGPRs (28 u64 = 56 VGPRs)
    u64 w0[4], u0[8], w1[8], u1[8];
#pragma unroll
    for (int w = 0; w < 4; ++w) w0[w] = w0b[tid * 4 + w];
#pragma unroll
    for (int w = 0; w < 8; ++w) u0[w] = u0b[tid * 8 + w];
#pragma unroll
    for (int w = 0; w < 8; ++w) w1[w] = w1b[tid * 8 + w];
#pragma unroll
    for (int w = 0; w < 8; ++w) u1[w] = u1b[tid * 8 + w];
    const float bi0 = bih0[tid], bh0 = bhh0[tid];
    const float bi1 = bih1[tid], bh1 = bhh1[tid];

    const int lane = tid & 63;
    const int wv = tid >> 6;

    __syncthreads();

    for (int t = 0; t < 512; ++t) {
        if (tid < 4) xb[tid] = embb[(u64)txt[t] * 4 + tid];
        __syncthreads();  // A: xb ready (also fences prev-iter h1s write)

        // ---- layer 0: acc = ((M + bih0) + bhh0) + HU, exact JAX association ----
        int mm0 = 0;
#pragma unroll
        for (int w = 0; w < 4; ++w) mm0 += __popcll(xb[w] ^ w0[w]);
        float c0 = ((float)(256 - 2 * mm0) + bi0) + bh0;
        float acc0;
        if (t == 0) {
            acc0 = c0;  // h0 = zeros -> HU term is exactly 0
        } else {
            int mh0 = 0;
#pragma unroll
            for (int w = 0; w < 8; ++w) mh0 += __popcll(h0s[w] ^ u0[w]);
            acc0 = c0 + (float)(512 - 2 * mh0);
        }
        u64 bal0 = __ballot(acc0 >= 0.0f);
        __syncthreads();  // B: all reads of h0s done
        if (lane == 0) h0s[wv] = bal0;
        __syncthreads();  // C: new h0 (= ys0[t]) visible

        // ---- layer 1: input is ys0[t] = h0s (just updated) ----
        int mx1 = 0;
#pragma unroll
        for (int w = 0; w < 8; ++w) mx1 += __popcll(h0s[w] ^ w1[w]);
        float c1 = ((float)(512 - 2 * mx1) + bi1) + bh1;
        float acc1;
        if (t == 0) {
            acc1 = c1;
        } else {
            int mh1 = 0;
#pragma unroll
            for (int w = 0; w < 8; ++w) mh1 += __popcll(h1s[w] ^ u1[w]);
            acc1 = c1 + (float)(512 - 2 * mh1);
        }
        u64 bal1 = __ballot(acc1 >= 0.0f);
        __syncthreads();  // D: all reads of h1s done
        if (lane == 0) h1s[wv] = bal1;
        // next iteration's barrier A fences this write before any reader
    }
    __syncthreads();
    if (tid < 8) {
        hT0[b * 8 + tid] = h0s[tid];
        hT1[b * 8 + tid] = h1s[tid];
    }
}

// ---------------- final dense: hidden @ sign(Wfc).T ----------------
__global__ void out_kernel(const u64* __restrict__ hT0, const u64* __restrict__ hT1,
                           const u64* __restrict__ wfcb, float* __restrict__ out) {
    int i = threadIdx.x;  // 0..127 : i = layer*64 + b
    if (i >= 128) return;
    const u64* h = (i < 64) ? (hT0 + i * 8) : (hT1 + (i - 64) * 8);
    int mm = 0;
#pragma unroll
    for (int w = 0; w < 8; ++w) mm += __popcll(h[w] ^ wfcb[w]);
    out[i] = (float)(512 - 2 * mm);
}

extern "C" void kernel_launch(void* const* d_in, const int* in_sizes, int n_in,
                              void* d_out, int out_size, void* d_ws, size_t ws_size,
                              hipStream_t stream) {
    const int* text = (const int*)d_in[0];
    // d_in[1] = text_lengths : unused by the reference computation
    const float* emb = (const float*)d_in[2];
    const float* Wih0 = (const float*)d_in[3];
    const float* Whh0 = (const float*)d_in[4];
    const float* bih0 = (const float*)d_in[5];
    const float* bhh0 = (const float*)d_in[6];
    const float* Wih1 = (const float*)d_in[7];
    const float* Whh1 = (const float*)d_in[8];
    const float* bih1 = (const float*)d_in[9];
    const float* bhh1 = (const float*)d_in[10];
    const float* Wfc = (const float*)d_in[11];
    float* out = (float*)d_out;

    // workspace layout (u64 units): [0..7]=amax scalar (+pad), then bit arrays
    u64* ws = (u64*)d_ws;
    u64* embb = ws + 8;            // 32000*4 = 128000 words
    u64* w0b = embb + 128000;      // 512*4   = 2048
    u64* u0b = w0b + 2048;         // 512*8   = 4096
    u64* w1b = u0b + 4096;         // 4096
    u64* u1b = w1b + 4096;         // 4096
    u64* wfcb = u1b + 4096;        // 8
    u64* hT0 = wfcb + 8;           // 64*8 = 512
    u64* hT1 = hT0 + 512;          // 512
    unsigned int* amax = (unsigned int*)d_ws;

    hipMemsetAsync(d_ws, 0, 64, stream);  // amax := 0 (ws is poisoned 0xAA)
    amax_kernel<<<1024, 256, 0, stream>>>(emb, amax);
    pack_kernel<<<(142344 + 255) / 256, 256, 0, stream>>>(emb, Wih0, Whh0, Wih1, Whh1, Wfc,
                                                          amax, embb, w0b, u0b, w1b, u1b, wfcb);
    scan_kernel<<<64, 512, 0, stream>>>(text, bih0, bhh0, bih1, bhh1,
                                        embb, w0b, u0b, w1b, u1b, hT0, hT1);
    out_kernel<<<1, 128, 0, stream>>>(hT0, hT1, wfcb, out);
}

// Round 2
// 602.646 us; speedup vs baseline: 1.1977x; 1.1977x over previous
//
#include <hip/hip_runtime.h>

typedef unsigned long long u64;

// Pass-through that makes the value asm-defined: the compiler cannot
// rematerialize the originating load inside the loop, so weights stay in VGPRs.
__device__ __forceinline__ u64 opaque64(u64 x) { asm volatile("" : "+v"(x)); return x; }

// ---------------- amax over |emb| ----------------
__global__ void amax_kernel(const float* __restrict__ emb, unsigned int* __restrict__ out) {
    const int n4 = (32000 * 256) / 4;
    float m = 0.0f;
    const float4* e4 = (const float4*)emb;
    for (int i = blockIdx.x * blockDim.x + threadIdx.x; i < n4; i += gridDim.x * blockDim.x) {
        float4 v = e4[i];
        m = fmaxf(m, fmaxf(fmaxf(fabsf(v.x), fabsf(v.y)), fmaxf(fabsf(v.z), fabsf(v.w))));
    }
#pragma unroll
    for (int off = 32; off > 0; off >>= 1) m = fmaxf(m, __shfl_down(m, off, 64));
    if ((threadIdx.x & 63) == 0) atomicMax(out, __float_as_uint(m));
}

// ---------------- bit packing, wave-cooperative ----------------
// One wave packs a 64-word chunk (4096 consecutive floats): per k, lanes read
// 64 consecutive floats (coalesced 256B), __ballot(sign) IS the packed word.
// Chunk->matrix mapping is uniform per chunk (all matrix word counts are
// multiples of 64 except Wfc, which is the single partial tail chunk).
__global__ void pack_kernel(const float* __restrict__ emb, const float* __restrict__ Wih0,
                            const float* __restrict__ Whh0, const float* __restrict__ Wih1,
                            const float* __restrict__ Whh1, const float* __restrict__ Wfc,
                            const unsigned int* __restrict__ amax_bits,
                            u64* __restrict__ embb, u64* __restrict__ w0b, u64* __restrict__ u0b,
                            u64* __restrict__ w1b, u64* __restrict__ u1b, u64* __restrict__ wfcb) {
    const int gw = (blockIdx.x * blockDim.x + threadIdx.x) >> 6;  // global wave id
    const int lane = threadIdx.x & 63;
    if (gw >= 2225) return;
    const long long wb = (long long)gw * 64;  // first packed word of this chunk

    const float* srcb; u64* dstb; int nw = 64; bool is_emb = false;
    if (wb < 128000)      { srcb = emb  + wb * 64;              dstb = embb + wb;            is_emb = true; }
    else if (wb < 130048) { srcb = Wih0 + (wb - 128000) * 64;   dstb = w0b + (wb - 128000); }
    else if (wb < 134144) { srcb = Whh0 + (wb - 130048) * 64;   dstb = u0b + (wb - 130048); }
    else if (wb < 138240) { srcb = Wih1 + (wb - 134144) * 64;   dstb = w1b + (wb - 134144); }
    else if (wb < 142336) { srcb = Whh1 + (wb - 138240) * 64;   dstb = u1b + (wb - 138240); }
    else                  { srcb = Wfc  + (wb - 142336) * 64;   dstb = wfcb + (wb - 142336); nw = 8; }

    float inv_s = 1.0f;
    if (is_emb) {
        float amax = __uint_as_float(*amax_bits) + 1e-12f;
        float s = exp2f(ceilf(log2f(amax / 127.0f)));   // power of two -> 1/s exact
        inv_s = 1.0f / s;
    }
    u64 mine = 0;
    for (int k = 0; k < nw; ++k) {
        float v = srcb[(long long)k * 64 + lane];
        bool bit = is_emb ? (rintf(v * inv_s) >= 0.0f)  // == rint(v/s), s = 2^e exact
                          : (v >= 0.0f);
        u64 bits = __ballot(bit);
        if (lane == k) mine = bits;
    }
    if (lane < nw) dstb[lane] = mine;   // coalesced 8B stores
}

// ---------------- sequential scan, both layers pipelined ----------------
// grid = B(64) blocks (1 per CU), block = H(512) threads = 8 waves (2/SIMD).
// Double-buffered h state -> 2 barriers/step; xb prefetched 1 step ahead into
// registers; all 28 u64 weight words pinned in VGPRs.
__global__ __launch_bounds__(512, 1) void scan_kernel(
    const int* __restrict__ text,
    const float* __restrict__ bih0, const float* __restrict__ bhh0,
    const float* __restrict__ bih1, const float* __restrict__ bhh1,
    const u64* __restrict__ embb, const u64* __restrict__ w0b, const u64* __restrict__ u0b,
    const u64* __restrict__ w1b, const u64* __restrict__ u1b, const u64* __restrict__ wfcb,
    float* __restrict__ out) {
    __shared__ int txt[512];
    __shared__ u64 h0s[2][8];   // layer-0 hidden bits, double-buffered
    __shared__ u64 h1s[2][8];   // layer-1 hidden bits, double-buffered

    const int tid = threadIdx.x;
    const int b = blockIdx.x;
    txt[tid] = text[b * 512 + tid];

    u64 w0[4], u0[8], w1[8], u1[8];
#pragma unroll
    for (int w = 0; w < 4; ++w) w0[w] = opaque64(w0b[tid * 4 + w]);
#pragma unroll
    for (int w = 0; w < 8; ++w) u0[w] = opaque64(u0b[tid * 8 + w]);
#pragma unroll
    for (int w = 0; w < 8; ++w) w1[w] = opaque64(w1b[tid * 8 + w]);
#pragma unroll
    for (int w = 0; w < 8; ++w) u1[w] = opaque64(u1b[tid * 8 + w]);
    const float bi0 = bih0[tid], bh0 = bhh0[tid];
    const float bi1 = bih1[tid], bh1 = bhh1[tid];

    if (tid < 8) { h0s[0][tid] = 0; h1s[0][tid] = 0; }
    const int lane = tid & 63;
    const int wv = tid >> 6;
    __syncthreads();

    const ulonglong2* e2 = (const ulonglong2*)embb;
    ulonglong2 xa = e2[(size_t)txt[0] * 2];       // same-address broadcast loads
    ulonglong2 xc = e2[(size_t)txt[0] * 2 + 1];

#pragma unroll 2
    for (int t = 0; t < 512; ++t) {
        const int r = t & 1;
        // prefetch next step's embedding bits (latency hidden behind this step)
        const int tokn = txt[(t + 1) & 511];
        ulonglong2 na = e2[(size_t)tokn * 2];
        ulonglong2 nc = e2[(size_t)tokn * 2 + 1];

        // recurrent popcounts for BOTH layers read old state (buffer r)
        int mh0 = 0, mh1 = 0;
#pragma unroll
        for (int w = 0; w < 8; ++w) mh0 += __popcll(h0s[r][w] ^ u0[w]);
#pragma unroll
        for (int w = 0; w < 8; ++w) mh1 += __popcll(h1s[r][w] ^ u1[w]);
        int mm0 = __popcll(xa.x ^ w0[0]) + __popcll(xa.y ^ w0[1])
                + __popcll(xc.x ^ w0[2]) + __popcll(xc.y ^ w0[3]);

        // acc0 = fl(fl(fl(M0+bih0)+bhh0)+HU0), exact JAX association
        float c0 = ((float)(256 - 2 * mm0) + bi0) + bh0;
        float acc0 = c0 + ((t == 0) ? 0.0f : (float)(512 - 2 * mh0));
        u64 bal0 = __ballot(acc0 >= 0.0f);
        if (lane == 0) h0s[r ^ 1][wv] = bal0;
        __syncthreads();   // A: old-state reads done + new h0 visible

        int mx1 = 0;
#pragma unroll
        for (int w = 0; w < 8; ++w) mx1 += __popcll(h0s[r ^ 1][w] ^ w1[w]);
        float c1 = ((float)(512 - 2 * mx1) + bi1) + bh1;
        float acc1 = c1 + ((t == 0) ? 0.0f : (float)(512 - 2 * mh1));
        u64 bal1 = __ballot(acc1 >= 0.0f);
        if (lane == 0) h1s[r ^ 1][wv] = bal1;
        __syncthreads();   // B: new h1 visible for next step's top reads

        xa = na; xc = nc;
    }

    // t=511 wrote buffers [0]; loop-end barrier already ordered them.
    // Fused final dense: out[layer*64 + b] = hT . sign(Wfc)
    if (tid < 2) {
        const u64* h = (tid == 0) ? h0s[0] : h1s[0];
        int mm = 0;
#pragma unroll
        for (int w = 0; w < 8; ++w) mm += __popcll(h[w] ^ wfcb[w]);
        out[tid * 64 + b] = (float)(512 - 2 * mm);
    }
}

extern "C" void kernel_launch(void* const* d_in, const int* in_sizes, int n_in,
                              void* d_out, int out_size, void* d_ws, size_t ws_size,
                              hipStream_t stream) {
    const int* text = (const int*)d_in[0];
    // d_in[1] = text_lengths : unused by the reference computation
    const float* emb = (const float*)d_in[2];
    const float* Wih0 = (const float*)d_in[3];
    const float* Whh0 = (const float*)d_in[4];
    const float* bih0 = (const float*)d_in[5];
    const float* bhh0 = (const float*)d_in[6];
    const float* Wih1 = (const float*)d_in[7];
    const float* Whh1 = (const float*)d_in[8];
    const float* bih1 = (const float*)d_in[9];
    const float* bhh1 = (const float*)d_in[10];
    const float* Wfc = (const float*)d_in[11];
    float* out = (float*)d_out;

    // workspace layout (u64 units): [0..7]=amax scalar (+pad), then bit arrays
    u64* ws = (u64*)d_ws;
    u64* embb = ws + 8;            // 32000*4 = 128000 words
    u64* w0b = embb + 128000;      // 512*4   = 2048
    u64* u0b = w0b + 2048;         // 512*8   = 4096
    u64* w1b = u0b + 4096;         // 4096
    u64* u1b = w1b + 4096;         // 4096
    u64* wfcb = u1b + 4096;        // 8
    unsigned int* amax = (unsigned int*)d_ws;

    hipMemsetAsync(d_ws, 0, 64, stream);  // amax := 0 (ws is poisoned 0xAA)
    amax_kernel<<<1024, 256, 0, stream>>>(emb, amax);
    pack_kernel<<<(2225 * 64 + 255) / 256, 256, 0, stream>>>(emb, Wih0, Whh0, Wih1, Whh1, Wfc,
                                                             amax, embb, w0b, u0b, w1b, u1b, wfcb);
    scan_kernel<<<64, 512, 0, stream>>>(text, bih0, bhh0, bih1, bhh1,
                                        embb, w0b, u0b, w1b, u1b, wfcb, out);
}